// Round 6
// baseline (352.135 us; speedup 1.0000x reference)
//
#include <hip/hip_runtime.h>
#include <hip/hip_bf16.h>
#include <math.h>

#define NB 16384
#define NF 32
#define ND 64
#define NIN 2048

typedef __attribute__((ext_vector_type(8))) short fragA;    // 8 bf16 (K=32 frags)
typedef __attribute__((ext_vector_type(4))) short frag16;   // 4 bf16 (K=16 frags)
typedef __attribute__((ext_vector_type(4))) float fragC;    // 4 fp32

#define MFMA(a, b, c) __builtin_amdgcn_mfma_f32_16x16x32_bf16((a), (b), (c), 0, 0, 0)

#if __has_builtin(__builtin_amdgcn_mfma_f32_16x16x16bf16_1k)
// device pass: real builtin (R5 log proved device accepts this spelling)
#define MFMA16(a, b, c) __builtin_amdgcn_mfma_f32_16x16x16bf16_1k((a), (b), (c), 0, 0, 0)
#else
// host pass only: builtin not declared for x86; body never executes on host.
#define MFMA16(a, b, c) (c)
#endif

__device__ __forceinline__ short f2bf(float f) {
    union { float f; unsigned u; } v; v.f = f;
    return (short)((v.u + 0x7fffu + ((v.u >> 16) & 1u)) >> 16);  // RNE
}
__device__ __forceinline__ fragA cvt8(const float* p) {
    const float4 a = *(const float4*)p;
    const float4 b = *(const float4*)(p + 4);
    union { __hip_bfloat162 h[4]; fragA f; } u;
    u.h[0] = __float22bfloat162_rn(make_float2(a.x, a.y));
    u.h[1] = __float22bfloat162_rn(make_float2(a.z, a.w));
    u.h[2] = __float22bfloat162_rn(make_float2(b.x, b.y));
    u.h[3] = __float22bfloat162_rn(make_float2(b.z, b.w));
    return u.f;
}
__device__ __forceinline__ frag16 cvt4(float v0, float v1, float v2, float v3) {
    union { __hip_bfloat162 h[2]; frag16 f; } u;
    u.h[0] = __float22bfloat162_rn(make_float2(v0, v1));
    u.h[1] = __float22bfloat162_rn(make_float2(v2, v3));
    return u.f;
}

__device__ __forceinline__ float frcp(float x) { return __builtin_amdgcn_rcpf(x); }
__device__ __forceinline__ float felu(float v) { return v > 0.f ? v : __expf(v) - 1.f; }
__device__ __forceinline__ float fsig(float g) { return __builtin_amdgcn_rcpf(1.f + __expf(-g)); }

// ---------------------------------------------------------------------------
// Prologue: weights -> fragment layouts in d_ws.
//   slots [0,16384)       fragA : w1 B-frags (= A-frags of w1^T)
//   slots [16384,65536)   frag16 pairs: w2/gw/lw A-frags of W^T (16x16x16)
//                         e = mat*32768 + f*1024 + nt2*256 + kc*64 + l
//                         val[j] = W[kc*16+(l>>4)*4+j][nt2*16+(l&15)]
//   slots [65536,90112)   fragA : mask big-GEMM frags (unchanged)
//   slots [90112,90624)   fragA : mw2/mgw/mlw2 (unchanged)
// ---------------------------------------------------------------------------
__global__ __launch_bounds__(256) void prep_kernel(
    const float* __restrict__ w1, const float* __restrict__ w2,
    const float* __restrict__ gw, const float* __restrict__ lw,
    const float* __restrict__ mw1, const float* __restrict__ mlw,
    const float* __restrict__ mw2, const float* __restrict__ mgw,
    const float* __restrict__ mlw2,
    short* __restrict__ wsout)
{
    int F = blockIdx.x * 256 + threadIdx.x;
    fragA o;
    if (F < 16384) {
        // w1 in B-frag (K=32) layout
        int f   = (F >> 9) & 31;
        int nt  = (F >> 7) & 3;
        int s   = (F >> 6) & 1;
        int l   = F & 63;
        const float* src = w1 + (size_t)f * 4096;
        int n  = nt * 16 + (l & 15);
        int k0 = s * 32 + ((l >> 4) << 3);
#pragma unroll
        for (int j = 0; j < 8; ++j) o[j] = f2bf(src[(k0 + j) * 64 + n]);
    } else if (F < 65536) {
        // w2/gw/lw in A-frag16 (W^T) layout: two frag16 entries per 16B slot
        int G = F - 16384;
        union { short s[8]; fragA a; } u;
#pragma unroll
        for (int h = 0; h < 2; ++h) {
            int e   = 2 * G + h;
            int l   = e & 63;
            int kc  = (e >> 6) & 3;
            int nt2 = (e >> 8) & 3;
            int f   = (e >> 10) & 31;
            int mat = e >> 15;                      // 0=w2 1=gw 2=lw
            const float* src = (mat == 0 ? w2 : mat == 1 ? gw : lw) + (size_t)f * 4096;
            int col = nt2 * 16 + (l & 15);
            int k0  = kc * 16 + ((l >> 4) << 2);
#pragma unroll
            for (int j = 0; j < 4; ++j) u.s[h * 4 + j] = f2bf(src[(k0 + j) * 64 + col]);
        }
        o = u.a;
    } else if (F < 90112) {
        int G  = F - 65536;
        int f  = G / 768;
        int r  = G - f * 768;
        int nt = r >> 7;
        int s  = (r >> 6) & 1;
        int l  = r & 63;
        int n  = nt * 16 + (l & 15);
        int k0 = f * 64 + s * 32 + ((l >> 4) << 3);
        if (n < 64) {
#pragma unroll
            for (int j = 0; j < 8; ++j) o[j] = f2bf(mw1[(size_t)(k0 + j) * 64 + n]);
        } else {
#pragma unroll
            for (int j = 0; j < 8; ++j) o[j] = f2bf(mlw[(size_t)(k0 + j) * 32 + (n - 64)]);
        }
    } else {
        int G2 = F - 90112;
        if (G2 < 256) {
            int nt = G2 >> 7, s = (G2 >> 6) & 1, l = G2 & 63;
            int n = nt * 16 + (l & 15);
            int k0 = s * 32 + ((l >> 4) << 3);
#pragma unroll
            for (int j = 0; j < 8; ++j) o[j] = f2bf(mw2[(k0 + j) * 32 + n]);
        } else {
            int G3 = G2 - 256;
            const float* src = (G3 < 128) ? mgw : mlw2;
            G3 &= 127;
            int nt = G3 >> 6, l = G3 & 63;
            int n = nt * 16 + (l & 15);
            int k0 = (l >> 4) << 3;
#pragma unroll
            for (int j = 0; j < 8; ++j) o[j] = f2bf(src[(k0 + j) * 32 + n]);
        }
    }
    ((fragA*)wsout)[F] = o;
}

// ---------------------------------------------------------------------------
// Fused kernel.  16 rows/block, 4 waves (256 threads) — R1 frame.
// Phase 2 is fully register-resident: GEMM1 computes H1^T via swapped
// operands (MFMA(wf, xfrag)); its D-layout IS the B-frag16 layout of H1^T,
// so GEMM2/3/4 run as 16x16x16 MFMAs with A = W^T frag16 from d_ws. No LDS
// round-trips; row index is lane-fast so LN reduces with 2 shuffles and all
// per-element tables (b1,b2,gb,lb,gamma,beta,xres) load as float4.
// LDS map (floats, total 8960 = 35,840 B -> 4 blocks/CU):
//   phase 1: redS [0,6208) 4x16x97 | hS1 [6208,7296) | resS [7296,7872)
//            h2S [7872,8448) | gS [0,576) lS [768,1344) (alias dead redS)
//   phase 2: outS [0,4096) 4 x 16x64 partials (all phase-1 regions dead)
//   maskS [8448,8960) persists phase 1 -> phase 2
// ---------------------------------------------------------------------------
__global__ __launch_bounds__(256, 4) void fused_kernel(
    const float* __restrict__ x,
    const short* __restrict__ wfrag, const short* __restrict__ mwfrag,
    const short* __restrict__ swfrag,
    const float* __restrict__ mb1, const float* __restrict__ mb2,
    const float* __restrict__ mlb, const float* __restrict__ mgb,
    const float* __restrict__ mlb2,
    const float* __restrict__ mgamma, const float* __restrict__ mbeta,
    const float* __restrict__ b1, const float* __restrict__ b2,
    const float* __restrict__ gb, const float* __restrict__ lb,
    const float* __restrict__ gamma, const float* __restrict__ beta,
    float* __restrict__ mask_out, float* __restrict__ out)
{
    __shared__ float smem[8960];
    float* redS  = smem;
    float* gS    = smem;
    float* lS    = smem + 768;
    float* hS1   = smem + 6208;
    float* resS  = smem + 7296;
    float* h2S   = smem + 7872;
    float* outS  = smem;            // phase 2
    float* maskS = smem + 8448;     // 512 floats

    const int tid = threadIdx.x;
    const int w = tid >> 6, l = tid & 63;
    const int row0 = blockIdx.x * 16;
    const int m = l & 15, q = l >> 4;

    const fragA*  wf   = (const fragA*)wfrag;
    const frag16* wf16 = (const frag16*)wfrag + 32768;   // slot 16384 * 2
    const fragA*  mwf  = (const fragA*)mwfrag;
    const fragA*  swf  = (const fragA*)swfrag;

    // ------------------------- Phase 1: mask -------------------------
    fragC acc[6];
#pragma unroll
    for (int nt = 0; nt < 6; ++nt) acc[nt] = (fragC){0.f, 0.f, 0.f, 0.f};

    const float* xpm = x + (size_t)(row0 + m) * NIN + q * 8;
    for (int fi = 0; fi < 8; ++fi) {
        int f = w * 8 + fi;
        const float* xp = xpm + f * ND;
        fragA a0 = cvt8(xp), a1 = cvt8(xp + 32);
        const size_t fb = (size_t)f * 768 + l;
#pragma unroll
        for (int nt = 0; nt < 6; ++nt) {
            acc[nt] = MFMA(a0, mwf[fb + nt * 128], acc[nt]);
            acc[nt] = MFMA(a1, mwf[fb + nt * 128 + 64], acc[nt]);
        }
    }
    {
        float* myred = redS + w * 1552;
#pragma unroll
        for (int nt = 0; nt < 6; ++nt)
#pragma unroll
            for (int rg = 0; rg < 4; ++rg)
                myred[(q * 4 + rg) * 97 + nt * 16 + m] = acc[nt][rg];
    }
    __syncthreads();

    // stage A: sum 4 wave-partials; h = elu(.+mb1) -> hS1 ; res -> resS
    {
        int r = tid & 15, cb = tid >> 4;
#pragma unroll
        for (int i = 0; i < 6; ++i) {
            int c = cb + i * 16;
            float s = redS[r * 97 + c]        + redS[1552 + r * 97 + c]
                    + redS[3104 + r * 97 + c] + redS[4656 + r * 97 + c];
            if (c < 64) {
                hS1[r * 68 + c] = felu(s + mb1[c]);
            } else {
                resS[r * 36 + (c - 64)] = s + mlb[c - 64];
            }
        }
    }
    __syncthreads();

    // stage B (MFMA, waves 0-1): h2 = h @ mw2 + mb2 -> h2S
    if (w < 2) {
        const float* ap = hS1 + m * 68 + q * 8;
        fragA a0 = cvt8(ap), a1 = cvt8(ap + 32);
        fragC c = {0.f, 0.f, 0.f, 0.f};
        c = MFMA(a0, swf[w * 128 + l], c);
        c = MFMA(a1, swf[w * 128 + 64 + l], c);
        float bv = mb2[w * 16 + m];
#pragma unroll
        for (int rg = 0; rg < 4; ++rg)
            h2S[(q * 4 + rg) * 36 + w * 16 + m] = c[rg] + bv;
    }
    __syncthreads();

    // stage C (MFMA, all 4 waves): gate (0-1) / lin (2-3) pre-acts
    {
        int ntc = w & 1;
        int isl = w >> 1;
        fragA a = cvt8(h2S + m * 36 + q * 8);          // K=32
        fragC c = {0.f, 0.f, 0.f, 0.f};
        c = MFMA(a, swf[256 + isl * 128 + ntc * 64 + l], c);
        float* dst = isl ? lS : gS;
#pragma unroll
        for (int rg = 0; rg < 4; ++rg)
            dst[(q * 4 + rg) * 36 + ntc * 16 + m] = c[rg];
    }
    __syncthreads();

    // stage D: pre = sigmoid(g+mgb)*(l+mlb2)+res ; LN(F=32)+softmax (wave 0)
    if (w == 0) {
        int r2 = l >> 2, c0 = (l & 3) * 8;
        float pre[8];
#pragma unroll
        for (int i = 0; i < 8; ++i) {
            int c = c0 + i;
            float gg = gS[r2 * 36 + c] + mgb[c];
            float ll = lS[r2 * 36 + c] + mlb2[c];
            pre[i] = ll * fsig(gg) + resS[r2 * 36 + c];
        }
        float s1 = 0.f, s2 = 0.f;
#pragma unroll
        for (int i = 0; i < 8; ++i) { s1 += pre[i]; s2 += pre[i] * pre[i]; }
        s1 += __shfl_xor(s1, 1); s2 += __shfl_xor(s2, 1);
        s1 += __shfl_xor(s1, 2); s2 += __shfl_xor(s2, 2);
        float mean = s1 * (1.f / 32.f);
        float var  = s2 * (1.f / 32.f) - mean * mean;
        float inv  = rsqrtf(fmaxf(var, 0.f) + 1e-5f);
        float ln[8]; float mx = -3.4e38f;
#pragma unroll
        for (int i = 0; i < 8; ++i) {
            ln[i] = (pre[i] - mean) * inv * mgamma[c0 + i] + mbeta[c0 + i];
            mx = fmaxf(mx, ln[i]);
        }
        mx = fmaxf(mx, __shfl_xor(mx, 1));
        mx = fmaxf(mx, __shfl_xor(mx, 2));
        float ssum = 0.f;
#pragma unroll
        for (int i = 0; i < 8; ++i) { ln[i] = __expf(ln[i] - mx); ssum += ln[i]; }
        ssum += __shfl_xor(ssum, 1); ssum += __shfl_xor(ssum, 2);
        float rs = frcp(ssum);
        float* mo = mask_out + (size_t)(row0 + r2) * 32 + c0;
        *(float4*)mo       = (float4){ln[0] * rs, ln[1] * rs, ln[2] * rs, ln[3] * rs};
        *(float4*)(mo + 4) = (float4){ln[4] * rs, ln[5] * rs, ln[6] * rs, ln[7] * rs};
#pragma unroll
        for (int i = 0; i < 8; ++i) maskS[r2 * 32 + c0 + i] = ln[i] * rs;
    }
    __syncthreads();

    // ------------------- Phase 2: register-resident GRNs -------------------
    fragC oac[4];
#pragma unroll
    for (int nt = 0; nt < 4; ++nt) oac[nt] = (fragC){0.f, 0.f, 0.f, 0.f};

    const int r = m;                       // this lane's batch row (lane-fast)
    const float* xrow = x + (size_t)(row0 + r) * NIN;

    for (int fi = 0; fi < 8; ++fi) {
        const int f = w * 8 + fi;
        const size_t base1 = (size_t)f * 512 + l;

        // GEMM1 (swapped): H1^T = W1^T . X^T
        const float* xp = xpm + f * ND;
        fragA a0 = cvt8(xp), a1 = cvt8(xp + 32);
        fragC h1[4];
#pragma unroll
        for (int nt = 0; nt < 4; ++nt) {
            fragC c = {0.f, 0.f, 0.f, 0.f};
            c = MFMA(wf[base1 + nt * 128], a0, c);
            c = MFMA(wf[base1 + nt * 128 + 64], a1, c);
            h1[nt] = c;
        }
        // bias + elu + pack: lane holds H1[r][nt*16+q*4+rg]
        frag16 h1b[4];
#pragma unroll
        for (int nt = 0; nt < 4; ++nt) {
            const float4 bv = *(const float4*)(b1 + f * 64 + nt * 16 + q * 4);
            h1b[nt] = cvt4(felu(h1[nt][0] + bv.x), felu(h1[nt][1] + bv.y),
                           felu(h1[nt][2] + bv.z), felu(h1[nt][3] + bv.w));
        }
        // GEMM2: H2^T = W2^T . H1^T  (16 x MFMA16, A from L2, B in regs)
        const frag16* w2p = wf16 + (size_t)f * 1024 + l;
        fragC h2[4];
#pragma unroll
        for (int nt2 = 0; nt2 < 4; ++nt2) {
            fragC c = {0.f, 0.f, 0.f, 0.f};
#pragma unroll
            for (int kc = 0; kc < 4; ++kc)
                c = MFMA16(w2p[nt2 * 256 + kc * 64], h1b[kc], c);
            h2[nt2] = c;
        }
        frag16 h2b[4];
#pragma unroll
        for (int nt2 = 0; nt2 < 4; ++nt2) {
            const float4 bv = *(const float4*)(b2 + f * 64 + nt2 * 16 + q * 4);
            h2b[nt2] = cvt4(h2[nt2][0] + bv.x, h2[nt2][1] + bv.y,
                            h2[nt2][2] + bv.z, h2[nt2][3] + bv.w);
        }
        // GEMM3+4: gate^T = GW^T . H2^T ; lin^T = LW^T . H2^T
        const frag16* gwp = wf16 + 32768 + (size_t)f * 1024 + l;
        const frag16* lwp = wf16 + 65536 + (size_t)f * 1024 + l;
        fragC ga[4], la[4];
#pragma unroll
        for (int nt = 0; nt < 4; ++nt) {
            fragC g = {0.f, 0.f, 0.f, 0.f}, li = {0.f, 0.f, 0.f, 0.f};
#pragma unroll
            for (int kc = 0; kc < 4; ++kc) {
                g  = MFMA16(gwp[nt * 256 + kc * 64], h2b[kc], g);
                li = MFMA16(lwp[nt * 256 + kc * 64], h2b[kc], li);
            }
            ga[nt] = g; la[nt] = li;
        }
        // epilogue: val = lin*sig(gate)+x ; LN over 64 cols (2 shuffles) ; +mask
        const float mk = maskS[r * 32 + f];
        float val[4][4];
        float s1 = 0.f, s2 = 0.f;
#pragma unroll
        for (int nt = 0; nt < 4; ++nt) {
            const float4 gbv = *(const float4*)(gb + f * 64 + nt * 16 + q * 4);
            const float4 lbv = *(const float4*)(lb + f * 64 + nt * 16 + q * 4);
            const float4 xr  = *(const float4*)(xrow + f * 64 + nt * 16 + q * 4);
#pragma unroll
            for (int rg = 0; rg < 4; ++rg) {
                float gg = ga[nt][rg] + ((const float*)&gbv)[rg];
                float ll = la[nt][rg] + ((const float*)&lbv)[rg];
                float vv = ll * fsig(gg) + ((const float*)&xr)[rg];
                val[nt][rg] = vv;
                s1 += vv; s2 += vv * vv;
            }
        }
        s1 += __shfl_xor(s1, 16); s2 += __shfl_xor(s2, 16);
        s1 += __shfl_xor(s1, 32); s2 += __shfl_xor(s2, 32);
        float mean = s1 * (1.f / 64.f);
        float var  = s2 * (1.f / 64.f) - mean * mean;
        float inv  = rsqrtf(fmaxf(var, 0.f) + 1e-5f);
#pragma unroll
        for (int nt = 0; nt < 4; ++nt) {
            const float4 gmv = *(const float4*)(gamma + f * 64 + nt * 16 + q * 4);
            const float4 btv = *(const float4*)(beta  + f * 64 + nt * 16 + q * 4);
#pragma unroll
            for (int rg = 0; rg < 4; ++rg) {
                float vec = (val[nt][rg] - mean) * inv * ((const float*)&gmv)[rg]
                          + ((const float*)&btv)[rg];
                oac[nt][rg] += mk * vec;
            }
        }
    }

    // cross-wave output reduction: lane holds out[r][nt*16+q*4+rg]
    __syncthreads();   // phase-1 LDS regions dead for ALL waves from here
#pragma unroll
    for (int nt = 0; nt < 4; ++nt)
        *(fragC*)(outS + w * 1024 + r * 64 + nt * 16 + q * 4) = oac[nt];
    __syncthreads();
    {
        int t4 = tid * 4;
        int rr = t4 >> 6, c = t4 & 63;
        float v[4];
#pragma unroll
        for (int j = 0; j < 4; ++j) {
            v[j] = outS[rr * 64 + c + j] + outS[1024 + rr * 64 + c + j]
                 + outS[2048 + rr * 64 + c + j] + outS[3072 + rr * 64 + c + j];
        }
        *(float4*)(out + (size_t)(row0 + rr) * 64 + c) = (float4){v[0], v[1], v[2], v[3]};
    }
}

// ---------------------------------------------------------------------------
extern "C" void kernel_launch(void* const* d_in, const int* in_sizes, int n_in,
                              void* d_out, int out_size, void* d_ws, size_t ws_size,
                              hipStream_t stream) {
    const float* x      = (const float*)d_in[0];
    const float* mw1    = (const float*)d_in[1];
    const float* mb1    = (const float*)d_in[2];
    const float* mw2    = (const float*)d_in[3];
    const float* mb2    = (const float*)d_in[4];
    const float* mlw    = (const float*)d_in[5];
    const float* mlb    = (const float*)d_in[6];
    const float* mgw    = (const float*)d_in[7];
    const float* mgb    = (const float*)d_in[8];
    const float* mlw2   = (const float*)d_in[9];
    const float* mlb2   = (const float*)d_in[10];
    const float* mgamma = (const float*)d_in[11];
    const float* mbeta  = (const float*)d_in[12];
    const float* w1     = (const float*)d_in[13];
    const float* b1     = (const float*)d_in[14];
    const float* w2     = (const float*)d_in[15];
    const float* b2     = (const float*)d_in[16];
    const float* gw     = (const float*)d_in[17];
    const float* gb     = (const float*)d_in[18];
    const float* lw     = (const float*)d_in[19];
    const float* lb     = (const float*)d_in[20];
    const float* gamma  = (const float*)d_in[21];
    const float* beta   = (const float*)d_in[22];

    float* out  = (float*)d_out;                 // [B,64]
    float* mask = out + (size_t)NB * 64;         // [B,32]

    short* wfrag  = (short*)d_ws;                // slots [0,65536): w1 + frag16 region
    short* mwfrag = wfrag + (size_t)65536 * 8;   // 24576 frags (mask big GEMM)
    short* swfrag = wfrag + (size_t)90112 * 8;   // 512 frags (mw2/mgw/mlw2)

    hipLaunchKernelGGL(prep_kernel, dim3(354), dim3(256), 0, stream,
                       w1, w2, gw, lw, mw1, mlw, mw2, mgw, mlw2, wfrag);
    hipLaunchKernelGGL(fused_kernel, dim3(NB / 16), dim3(256), 0, stream,
                       x, wfrag, mwfrag, swfrag,
                       mb1, mb2, mlb, mgb, mlb2, mgamma, mbeta,
                       b1, b2, gb, lb, gamma, beta,
                       mask, out);
}

// Round 8
// 329.304 us; speedup vs baseline: 1.0693x; 1.0693x over previous
//
#include <hip/hip_runtime.h>
#include <hip/hip_bf16.h>
#include <math.h>

#define NB 16384
#define NF 32
#define ND 64
#define NIN 2048

typedef __attribute__((ext_vector_type(8))) short fragA;    // 8 bf16 (16B)
typedef __attribute__((ext_vector_type(4))) short frag16;   // 4 bf16 (8B)
typedef __attribute__((ext_vector_type(4))) float fragC;    // 4 fp32

#define MFMA(a, b, c) __builtin_amdgcn_mfma_f32_16x16x32_bf16((a), (b), (c), 0, 0, 0)

#if __has_builtin(__builtin_amdgcn_mfma_f32_16x16x16bf16_1k)
#define MFMA16(a, b, c) __builtin_amdgcn_mfma_f32_16x16x16bf16_1k((a), (b), (c), 0, 0, 0)
#else
// host pass only: never executes
#define MFMA16(a, b, c) (c)
#endif

// lo/hi frag16 halves of a 16B fragA (pure register aliasing, no VALU)
#define FLO(v) __builtin_shufflevector((v), (v), 0, 1, 2, 3)
#define FHI(v) __builtin_shufflevector((v), (v), 4, 5, 6, 7)

__device__ __forceinline__ short f2bf(float f) {
    union { float f; unsigned u; } v; v.f = f;
    return (short)((v.u + 0x7fffu + ((v.u >> 16) & 1u)) >> 16);  // RNE
}
__device__ __forceinline__ fragA cvt8(const float* p) {
    const float4 a = *(const float4*)p;
    const float4 b = *(const float4*)(p + 4);
    union { __hip_bfloat162 h[4]; fragA f; } u;
    u.h[0] = __float22bfloat162_rn(make_float2(a.x, a.y));
    u.h[1] = __float22bfloat162_rn(make_float2(a.z, a.w));
    u.h[2] = __float22bfloat162_rn(make_float2(b.x, b.y));
    u.h[3] = __float22bfloat162_rn(make_float2(b.z, b.w));
    return u.f;
}
__device__ __forceinline__ frag16 cvt4(float v0, float v1, float v2, float v3) {
    union { __hip_bfloat162 h[2]; frag16 f; } u;
    u.h[0] = __float22bfloat162_rn(make_float2(v0, v1));
    u.h[1] = __float22bfloat162_rn(make_float2(v2, v3));
    return u.f;
}

__device__ __forceinline__ float frcp(float x) { return __builtin_amdgcn_rcpf(x); }
__device__ __forceinline__ float felu(float v) { return v > 0.f ? v : __expf(v) - 1.f; }
__device__ __forceinline__ float fsig(float g) { return __builtin_amdgcn_rcpf(1.f + __expf(-g)); }

// ---------------------------------------------------------------------------
// Prologue: weights -> fragment layouts in d_ws.
//   slots [0,16384)     fragA : w1 B-frags (= A-frags of w1^T)
//   slots [16384,65536) fragA : w2/gw/lw A-frag16 PAIRS of W^T.
//        slot = 16384 + mat*16384 + f*512 + nt2*128 + p*64 + l  (mat:0=w2,1=gw,2=lw)
//        shorts[h*4+j] = W[(2p+h)*16 + (l>>4)*4 + j][nt2*16 + (l&15)]
//        (one 16B load = frag16 for kc=2p and kc=2p+1)
//   slots [65536,90112) fragA : mask big-GEMM frags (unchanged)
//   slots [90112,90624) fragA : mw2/mgw/mlw2 (unchanged)
// ---------------------------------------------------------------------------
__global__ __launch_bounds__(256) void prep_kernel(
    const float* __restrict__ w1, const float* __restrict__ w2,
    const float* __restrict__ gw, const float* __restrict__ lw,
    const float* __restrict__ mw1, const float* __restrict__ mlw,
    const float* __restrict__ mw2, const float* __restrict__ mgw,
    const float* __restrict__ mlw2,
    short* __restrict__ wsout)
{
    int F = blockIdx.x * 256 + threadIdx.x;
    fragA o;
    if (F < 16384) {
        // w1 in B-frag (K=32) layout
        int f   = (F >> 9) & 31;
        int nt  = (F >> 7) & 3;
        int s   = (F >> 6) & 1;
        int l   = F & 63;
        const float* src = w1 + (size_t)f * 4096;
        int n  = nt * 16 + (l & 15);
        int k0 = s * 32 + ((l >> 4) << 3);
#pragma unroll
        for (int j = 0; j < 8; ++j) o[j] = f2bf(src[(k0 + j) * 64 + n]);
    } else if (F < 65536) {
        // w2/gw/lw A-frag16 pairs (see header comment)
        int G   = F - 16384;
        int mat = G >> 14;
        int rem = G & 16383;
        int f   = rem >> 9;
        int nt2 = (rem >> 7) & 3;
        int p   = (rem >> 6) & 1;
        int l   = rem & 63;
        const float* src = (mat == 0 ? w2 : mat == 1 ? gw : lw) + (size_t)f * 4096;
        int col = nt2 * 16 + (l & 15);
        union { short s[8]; fragA a; } u;
#pragma unroll
        for (int h = 0; h < 2; ++h) {
            int k0 = (2 * p + h) * 16 + ((l >> 4) << 2);
#pragma unroll
            for (int j = 0; j < 4; ++j) u.s[h * 4 + j] = f2bf(src[(k0 + j) * 64 + col]);
        }
        o = u.a;
    } else if (F < 90112) {
        int G  = F - 65536;
        int f  = G / 768;
        int r  = G - f * 768;
        int nt = r >> 7;
        int s  = (r >> 6) & 1;
        int l  = r & 63;
        int n  = nt * 16 + (l & 15);
        int k0 = f * 64 + s * 32 + ((l >> 4) << 3);
        if (n < 64) {
#pragma unroll
            for (int j = 0; j < 8; ++j) o[j] = f2bf(mw1[(size_t)(k0 + j) * 64 + n]);
        } else {
#pragma unroll
            for (int j = 0; j < 8; ++j) o[j] = f2bf(mlw[(size_t)(k0 + j) * 32 + (n - 64)]);
        }
    } else {
        int G2 = F - 90112;
        if (G2 < 256) {
            int nt = G2 >> 7, s = (G2 >> 6) & 1, l = G2 & 63;
            int n = nt * 16 + (l & 15);
            int k0 = s * 32 + ((l >> 4) << 3);
#pragma unroll
            for (int j = 0; j < 8; ++j) o[j] = f2bf(mw2[(k0 + j) * 32 + n]);
        } else {
            int G3 = G2 - 256;
            const float* src = (G3 < 128) ? mgw : mlw2;
            G3 &= 127;
            int nt = G3 >> 6, l = G3 & 63;
            int n = nt * 16 + (l & 15);
            int k0 = (l >> 4) << 3;
#pragma unroll
            for (int j = 0; j < 8; ++j) o[j] = f2bf(src[(k0 + j) * 32 + n]);
        }
    }
    ((fragA*)wsout)[F] = o;
}

// ---------------------------------------------------------------------------
// Fused kernel.  16 rows/block, 4 waves (256 threads).
// Phase 2 register-resident (R6 structure) + R7 load pipeline:
//   - all weight fetches are 16B fragA loads into explicit prefetch arrays
//   - w2r issued before GEMM1 MFMAs; gwr before h1 pack; lwr+xres before
//     h2 pack -> each ~200cy L2 batch hides under the preceding compute.
// LDS map unchanged (35,840 B -> 4 blocks/CU).
// ---------------------------------------------------------------------------
__global__ __launch_bounds__(256, 4) void fused_kernel(
    const float* __restrict__ x,
    const short* __restrict__ wfrag, const short* __restrict__ mwfrag,
    const short* __restrict__ swfrag,
    const float* __restrict__ mb1, const float* __restrict__ mb2,
    const float* __restrict__ mlb, const float* __restrict__ mgb,
    const float* __restrict__ mlb2,
    const float* __restrict__ mgamma, const float* __restrict__ mbeta,
    const float* __restrict__ b1, const float* __restrict__ b2,
    const float* __restrict__ gb, const float* __restrict__ lb,
    const float* __restrict__ gamma, const float* __restrict__ beta,
    float* __restrict__ mask_out, float* __restrict__ out)
{
    __shared__ float smem[8960];
    float* redS  = smem;
    float* gS    = smem;
    float* lS    = smem + 768;
    float* hS1   = smem + 6208;
    float* resS  = smem + 7296;
    float* h2S   = smem + 7872;
    float* outS  = smem;            // phase 2
    float* maskS = smem + 8448;     // 512 floats

    const int tid = threadIdx.x;
    const int w = tid >> 6, l = tid & 63;
    const int row0 = blockIdx.x * 16;
    const int m = l & 15, q = l >> 4;

    const fragA* wf  = (const fragA*)wfrag;
    const fragA* mwf = (const fragA*)mwfrag;
    const fragA* swf = (const fragA*)swfrag;

    // ------------------------- Phase 1: mask -------------------------
    fragC acc[6];
#pragma unroll
    for (int nt = 0; nt < 6; ++nt) acc[nt] = (fragC){0.f, 0.f, 0.f, 0.f};

    const float* xpm = x + (size_t)(row0 + m) * NIN + q * 8;
    for (int fi = 0; fi < 8; ++fi) {
        int f = w * 8 + fi;
        const float* xp = xpm + f * ND;
        fragA a0 = cvt8(xp), a1 = cvt8(xp + 32);
        const size_t fb = (size_t)f * 768 + l;
#pragma unroll
        for (int nt = 0; nt < 6; ++nt) {
            acc[nt] = MFMA(a0, mwf[fb + nt * 128], acc[nt]);
            acc[nt] = MFMA(a1, mwf[fb + nt * 128 + 64], acc[nt]);
        }
    }
    {
        float* myred = redS + w * 1552;
#pragma unroll
        for (int nt = 0; nt < 6; ++nt)
#pragma unroll
            for (int rg = 0; rg < 4; ++rg)
                myred[(q * 4 + rg) * 97 + nt * 16 + m] = acc[nt][rg];
    }
    __syncthreads();

    // stage A: sum 4 wave-partials; h = elu(.+mb1) -> hS1 ; res -> resS
    {
        int r = tid & 15, cb = tid >> 4;
#pragma unroll
        for (int i = 0; i < 6; ++i) {
            int c = cb + i * 16;
            float s = redS[r * 97 + c]        + redS[1552 + r * 97 + c]
                    + redS[3104 + r * 97 + c] + redS[4656 + r * 97 + c];
            if (c < 64) {
                hS1[r * 68 + c] = felu(s + mb1[c]);
            } else {
                resS[r * 36 + (c - 64)] = s + mlb[c - 64];
            }
        }
    }
    __syncthreads();

    // stage B (MFMA, waves 0-1): h2 = h @ mw2 + mb2 -> h2S
    if (w < 2) {
        const float* ap = hS1 + m * 68 + q * 8;
        fragA a0 = cvt8(ap), a1 = cvt8(ap + 32);
        fragC c = {0.f, 0.f, 0.f, 0.f};
        c = MFMA(a0, swf[w * 128 + l], c);
        c = MFMA(a1, swf[w * 128 + 64 + l], c);
        float bv = mb2[w * 16 + m];
#pragma unroll
        for (int rg = 0; rg < 4; ++rg)
            h2S[(q * 4 + rg) * 36 + w * 16 + m] = c[rg] + bv;
    }
    __syncthreads();

    // stage C (MFMA, all 4 waves): gate (0-1) / lin (2-3) pre-acts
    {
        int ntc = w & 1;
        int isl = w >> 1;
        fragA a = cvt8(h2S + m * 36 + q * 8);          // K=32
        fragC c = {0.f, 0.f, 0.f, 0.f};
        c = MFMA(a, swf[256 + isl * 128 + ntc * 64 + l], c);
        float* dst = isl ? lS : gS;
#pragma unroll
        for (int rg = 0; rg < 4; ++rg)
            dst[(q * 4 + rg) * 36 + ntc * 16 + m] = c[rg];
    }
    __syncthreads();

    // stage D: pre = sigmoid(g+mgb)*(l+mlb2)+res ; LN(F=32)+softmax (wave 0)
    if (w == 0) {
        int r2 = l >> 2, c0 = (l & 3) * 8;
        float pre[8];
#pragma unroll
        for (int i = 0; i < 8; ++i) {
            int c = c0 + i;
            float gg = gS[r2 * 36 + c] + mgb[c];
            float ll = lS[r2 * 36 + c] + mlb2[c];
            pre[i] = ll * fsig(gg) + resS[r2 * 36 + c];
        }
        float s1 = 0.f, s2 = 0.f;
#pragma unroll
        for (int i = 0; i < 8; ++i) { s1 += pre[i]; s2 += pre[i] * pre[i]; }
        s1 += __shfl_xor(s1, 1); s2 += __shfl_xor(s2, 1);
        s1 += __shfl_xor(s1, 2); s2 += __shfl_xor(s2, 2);
        float mean = s1 * (1.f / 32.f);
        float var  = s2 * (1.f / 32.f) - mean * mean;
        float inv  = rsqrtf(fmaxf(var, 0.f) + 1e-5f);
        float ln[8]; float mx = -3.4e38f;
#pragma unroll
        for (int i = 0; i < 8; ++i) {
            ln[i] = (pre[i] - mean) * inv * mgamma[c0 + i] + mbeta[c0 + i];
            mx = fmaxf(mx, ln[i]);
        }
        mx = fmaxf(mx, __shfl_xor(mx, 1));
        mx = fmaxf(mx, __shfl_xor(mx, 2));
        float ssum = 0.f;
#pragma unroll
        for (int i = 0; i < 8; ++i) { ln[i] = __expf(ln[i] - mx); ssum += ln[i]; }
        ssum += __shfl_xor(ssum, 1); ssum += __shfl_xor(ssum, 2);
        float rs = frcp(ssum);
        float* mo = mask_out + (size_t)(row0 + r2) * 32 + c0;
        *(float4*)mo       = (float4){ln[0] * rs, ln[1] * rs, ln[2] * rs, ln[3] * rs};
        *(float4*)(mo + 4) = (float4){ln[4] * rs, ln[5] * rs, ln[6] * rs, ln[7] * rs};
#pragma unroll
        for (int i = 0; i < 8; ++i) maskS[r2 * 32 + c0 + i] = ln[i] * rs;
    }
    __syncthreads();

    // ------------------- Phase 2: register-resident GRNs -------------------
    fragC oac[4];
#pragma unroll
    for (int nt = 0; nt < 4; ++nt) oac[nt] = (fragC){0.f, 0.f, 0.f, 0.f};

    const int r = m;                       // this lane's batch row (lane-fast)
    const float* xrow = x + (size_t)(row0 + r) * NIN;

    for (int fi = 0; fi < 8; ++fi) {
        const int f = w * 8 + fi;
        const size_t base1 = (size_t)f * 512 + l;
        // paired-frag16 bases (fragA units)
        const fragA* w2q = wf + 16384 + (size_t)f * 512 + l;
        const fragA* gwq = w2q + 16384;
        const fragA* lwq = w2q + 32768;

        // GEMM1 inputs
        fragA w1r[8];
#pragma unroll
        for (int nt = 0; nt < 4; ++nt) {
            w1r[nt * 2]     = wf[base1 + nt * 128];
            w1r[nt * 2 + 1] = wf[base1 + nt * 128 + 64];
        }
        const float* xp = xpm + f * ND;
        fragA a0 = cvt8(xp), a1 = cvt8(xp + 32);

        // prefetch GEMM2 weights: latency hides under GEMM1 MFMAs
        fragA w2r[8];
#pragma unroll
        for (int i = 0; i < 8; ++i) w2r[i] = w2q[i * 64];

        // GEMM1 (swapped): H1^T = W1^T . X^T
        fragC h1[4];
#pragma unroll
        for (int nt = 0; nt < 4; ++nt) {
            fragC c = {0.f, 0.f, 0.f, 0.f};
            c = MFMA(w1r[nt * 2], a0, c);
            c = MFMA(w1r[nt * 2 + 1], a1, c);
            h1[nt] = c;
        }

        // prefetch GEMM3 weights: hides under h1 pack + GEMM2
        fragA gwr[8];
#pragma unroll
        for (int i = 0; i < 8; ++i) gwr[i] = gwq[i * 64];

        // bias + elu + pack: lane holds H1[r][nt*16+q*4+rg]
        frag16 h1b[4];
#pragma unroll
        for (int nt = 0; nt < 4; ++nt) {
            const float4 bv = *(const float4*)(b1 + f * 64 + nt * 16 + q * 4);
            h1b[nt] = cvt4(felu(h1[nt][0] + bv.x), felu(h1[nt][1] + bv.y),
                           felu(h1[nt][2] + bv.z), felu(h1[nt][3] + bv.w));
        }

        // GEMM2: H2^T = W2^T . H1^T (paired frag16 A-operands, B in regs)
        fragC h2[4];
#pragma unroll
        for (int nt2 = 0; nt2 < 4; ++nt2) {
            fragC c = {0.f, 0.f, 0.f, 0.f};
            c = MFMA16(FLO(w2r[nt2 * 2]),     h1b[0], c);
            c = MFMA16(FHI(w2r[nt2 * 2]),     h1b[1], c);
            c = MFMA16(FLO(w2r[nt2 * 2 + 1]), h1b[2], c);
            c = MFMA16(FHI(w2r[nt2 * 2 + 1]), h1b[3], c);
            h2[nt2] = c;
        }

        // prefetch GEMM4 weights + residual: hides under h2 pack + GEMM3
        fragA lwr[8];
#pragma unroll
        for (int i = 0; i < 8; ++i) lwr[i] = lwq[i * 64];
        float4 xr[4];
#pragma unroll
        for (int nt = 0; nt < 4; ++nt)
            xr[nt] = *(const float4*)(xrow + f * 64 + nt * 16 + q * 4);

        frag16 h2b[4];
#pragma unroll
        for (int nt2 = 0; nt2 < 4; ++nt2) {
            const float4 bv = *(const float4*)(b2 + f * 64 + nt2 * 16 + q * 4);
            h2b[nt2] = cvt4(h2[nt2][0] + bv.x, h2[nt2][1] + bv.y,
                            h2[nt2][2] + bv.z, h2[nt2][3] + bv.w);
        }

        // GEMM3+4: gate^T = GW^T . H2^T ; lin^T = LW^T . H2^T
        fragC ga[4], la[4];
#pragma unroll
        for (int nt = 0; nt < 4; ++nt) {
            fragC g = {0.f, 0.f, 0.f, 0.f}, li = {0.f, 0.f, 0.f, 0.f};
            g  = MFMA16(FLO(gwr[nt * 2]),     h2b[0], g);
            g  = MFMA16(FHI(gwr[nt * 2]),     h2b[1], g);
            g  = MFMA16(FLO(gwr[nt * 2 + 1]), h2b[2], g);
            g  = MFMA16(FHI(gwr[nt * 2 + 1]), h2b[3], g);
            li = MFMA16(FLO(lwr[nt * 2]),     h2b[0], li);
            li = MFMA16(FHI(lwr[nt * 2]),     h2b[1], li);
            li = MFMA16(FLO(lwr[nt * 2 + 1]), h2b[2], li);
            li = MFMA16(FHI(lwr[nt * 2 + 1]), h2b[3], li);
            ga[nt] = g; la[nt] = li;
        }

        // epilogue: val = lin*sig(gate)+x ; LN over 64 cols (2 shuffles) ; +mask
        const float mk = maskS[r * 32 + f];
        float val[4][4];
        float s1 = 0.f, s2 = 0.f;
#pragma unroll
        for (int nt = 0; nt < 4; ++nt) {
            const float4 gbv = *(const float4*)(gb + f * 64 + nt * 16 + q * 4);
            const float4 lbv = *(const float4*)(lb + f * 64 + nt * 16 + q * 4);
#pragma unroll
            for (int rg = 0; rg < 4; ++rg) {
                float gg = ga[nt][rg] + ((const float*)&gbv)[rg];
                float ll = la[nt][rg] + ((const float*)&lbv)[rg];
                float vv = ll * fsig(gg) + ((const float*)&xr[nt])[rg];
                val[nt][rg] = vv;
                s1 += vv; s2 += vv * vv;
            }
        }
        s1 += __shfl_xor(s1, 16); s2 += __shfl_xor(s2, 16);
        s1 += __shfl_xor(s1, 32); s2 += __shfl_xor(s2, 32);
        float mean = s1 * (1.f / 64.f);
        float var  = s2 * (1.f / 64.f) - mean * mean;
        float inv  = rsqrtf(fmaxf(var, 0.f) + 1e-5f);
#pragma unroll
        for (int nt = 0; nt < 4; ++nt) {
            const float4 gmv = *(const float4*)(gamma + f * 64 + nt * 16 + q * 4);
            const float4 btv = *(const float4*)(beta  + f * 64 + nt * 16 + q * 4);
#pragma unroll
            for (int rg = 0; rg < 4; ++rg) {
                float vec = (val[nt][rg] - mean) * inv * ((const float*)&gmv)[rg]
                          + ((const float*)&btv)[rg];
                oac[nt][rg] += mk * vec;
            }
        }
    }

    // cross-wave output reduction: lane holds out[r][nt*16+q*4+rg]
    __syncthreads();   // phase-1 LDS regions dead for ALL waves from here
#pragma unroll
    for (int nt = 0; nt < 4; ++nt)
        *(fragC*)(outS + w * 1024 + r * 64 + nt * 16 + q * 4) = oac[nt];
    __syncthreads();
    {
        int t4 = tid * 4;
        int rr = t4 >> 6, c = t4 & 63;
        float v[4];
#pragma unroll
        for (int j = 0; j < 4; ++j) {
            v[j] = outS[rr * 64 + c + j] + outS[1024 + rr * 64 + c + j]
                 + outS[2048 + rr * 64 + c + j] + outS[3072 + rr * 64 + c + j];
        }
        *(float4*)(out + (size_t)(row0 + rr) * 64 + c) = (float4){v[0], v[1], v[2], v[3]};
    }
}

// ---------------------------------------------------------------------------
extern "C" void kernel_launch(void* const* d_in, const int* in_sizes, int n_in,
                              void* d_out, int out_size, void* d_ws, size_t ws_size,
                              hipStream_t stream) {
    const float* x      = (const float*)d_in[0];
    const float* mw1    = (const float*)d_in[1];
    const float* mb1    = (const float*)d_in[2];
    const float* mw2    = (const float*)d_in[3];
    const float* mb2    = (const float*)d_in[4];
    const float* mlw    = (const float*)d_in[5];
    const float* mlb    = (const float*)d_in[6];
    const float* mgw    = (const float*)d_in[7];
    const float* mgb    = (const float*)d_in[8];
    const float* mlw2   = (const float*)d_in[9];
    const float* mlb2   = (const float*)d_in[10];
    const float* mgamma = (const float*)d_in[11];
    const float* mbeta  = (const float*)d_in[12];
    const float* w1     = (const float*)d_in[13];
    const float* b1     = (const float*)d_in[14];
    const float* w2     = (const float*)d_in[15];
    const float* b2     = (const float*)d_in[16];
    const float* gw     = (const float*)d_in[17];
    const float* gb     = (const float*)d_in[18];
    const float* lw     = (const float*)d_in[19];
    const float* lb     = (const float*)d_in[20];
    const float* gamma  = (const float*)d_in[21];
    const float* beta   = (const float*)d_in[22];

    float* out  = (float*)d_out;                 // [B,64]
    float* mask = out + (size_t)NB * 64;         // [B,32]

    short* wfrag  = (short*)d_ws;                // slots [0,65536): w1 + paired frag16
    short* mwfrag = wfrag + (size_t)65536 * 8;   // 24576 frags (mask big GEMM)
    short* swfrag = wfrag + (size_t)90112 * 8;   // 512 frags (mw2/mgw/mlw2)

    hipLaunchKernelGGL(prep_kernel, dim3(354), dim3(256), 0, stream,
                       w1, w2, gw, lw, mw1, mlw, mw2, mgw, mlw2, wfrag);
    hipLaunchKernelGGL(fused_kernel, dim3(NB / 16), dim3(256), 0, stream,
                       x, wfrag, mwfrag, swfrag,
                       mb1, mb2, mlb, mgb, mlb2, mgamma, mbeta,
                       b1, b2, gb, lb, gamma, beta,
                       mask, out);
}